// Round 5
// baseline (262.987 us; speedup 1.0000x reference)
//
#include <hip/hip_runtime.h>

// Problem constants (match reference)
#define N_NODES 100000
#define N_EDGES 1200000
#define DIM     64
#define BGRAPHS 1000
#define NCLASS  10
#define BN_EPS  1e-5f

// CSR-build partition constants
#define NBUCK   256            // coarse buckets
#define NPB     391            // nodes per bucket (256*391 = 100096 >= N)
#define MAGIC   10984572u      // ceil(2^32/391): bucket = umulhi(d, MAGIC)
#define CHUNK   8192           // edges per partition block
#define NBLK_P  147            // ceil(E / CHUNK)
#define SCAN_N  (NBUCK * NBLK_P)   // 37632
#define CAP     8192           // refine LDS staging capacity (>= max bucket edges)

typedef __attribute__((ext_vector_type(8))) short   bfx8;   // 8 bf16 MFMA A/B frag
typedef __attribute__((ext_vector_type(4))) float   f32x4;  // MFMA C/D frag
typedef __attribute__((ext_vector_type(8))) unsigned short u16x8;

__device__ __forceinline__ unsigned short f2bf(float f) {
    unsigned u = __builtin_bit_cast(unsigned, f);
    unsigned r = (u + 0x7FFFu + ((u >> 16) & 1u)) >> 16;   // RNE
    return (unsigned short)r;
}
__device__ __forceinline__ float bf2f(unsigned short h) {
    unsigned u = ((unsigned)h) << 16;
    return __builtin_bit_cast(float, u);
}

// ---------------------------------------------------------------------------
// fp32 -> bf16 convert (8 floats/thread) + zero xs
// ---------------------------------------------------------------------------
__global__ void convert_kernel(const float* __restrict__ x, unsigned short* __restrict__ xb,
                               float* __restrict__ xs) {
    int i = blockIdx.x * blockDim.x + threadIdx.x;
    const int n8 = N_NODES * DIM / 8;
    if (i < n8) {
        float4 a = ((const float4*)x)[i * 2];
        float4 b = ((const float4*)x)[i * 2 + 1];
        u16x8 o;
        o[0] = f2bf(a.x); o[1] = f2bf(a.y); o[2] = f2bf(a.z); o[3] = f2bf(a.w);
        o[4] = f2bf(b.x); o[5] = f2bf(b.y); o[6] = f2bf(b.z); o[7] = f2bf(b.w);
        ((u16x8*)xb)[i] = o;
    }
    if (i < BGRAPHS * DIM) xs[i] = 0.f;
}

// ---------------------------------------------------------------------------
// Prep: pack W1a/W1b/W2 transposed to bf16 (wp[col*64+k] = W[k][col]) and
// fold BN scale/shift: s = g*rsqrt(v+eps); o = b*s + be - m*s
// ---------------------------------------------------------------------------
__global__ void prep_kernel(const float* __restrict__ W1a, const float* __restrict__ W1b,
                            const float* __restrict__ W2,
                            const float* __restrict__ b1a,
                            const float* __restrict__ g1, const float* __restrict__ be1,
                            const float* __restrict__ m1, const float* __restrict__ v1,
                            const float* __restrict__ b2,
                            const float* __restrict__ g2, const float* __restrict__ be2,
                            const float* __restrict__ m2, const float* __restrict__ v2,
                            unsigned short* __restrict__ wpA, unsigned short* __restrict__ wpB,
                            unsigned short* __restrict__ wpC,
                            float* __restrict__ s1, float* __restrict__ o1,
                            float* __restrict__ s2, float* __restrict__ o2) {
    int t = blockIdx.x * blockDim.x + threadIdx.x;
    if (t < 3 * 4096) {
        int mat = t >> 12, i = t & 4095;
        int col = i >> 6, k = i & 63;
        const float* W = (mat == 0) ? W1a : ((mat == 1) ? W1b : W2);
        unsigned short* wp = (mat == 0) ? wpA : ((mat == 1) ? wpB : wpC);
        wp[i] = f2bf(W[k * 64 + col]);
    }
    if (t < 64) {
        float s = g1[t] * rsqrtf(v1[t] + BN_EPS);
        s1[t] = s;
        o1[t] = b1a[t] * s + (be1[t] - m1[t] * s);
        float s2v = g2[t] * rsqrtf(v2[t] + BN_EPS);
        s2[t] = s2v;
        o2[t] = b2[t] * s2v + (be2[t] - m2[t] * s2v);
    }
}

// ---------------------------------------------------------------------------
// Phase A: per-(block,bucket) histogram via LDS; hist[bucket*NBLK_P + blk]
// ---------------------------------------------------------------------------
__global__ __launch_bounds__(256) void histA_kernel(const int* __restrict__ ei,
                                                    int* __restrict__ hist) {
    __shared__ int cnt[NBUCK];
    int t = threadIdx.x, blk = blockIdx.x;
    cnt[t] = 0;
    __syncthreads();
    int e0 = blk * CHUNK;
    for (int i = t; i < CHUNK; i += 256) {
        int e = e0 + i;
        if (e >= N_EDGES) break;
        unsigned d = (unsigned)ei[N_EDGES + e];
        int b = __umulhi(d, MAGIC);
        atomicAdd(&cnt[b], 1);
    }
    __syncthreads();
    hist[t * NBLK_P + blk] = cnt[t];
}

// ---------------------------------------------------------------------------
// Scan step 1: per-block (1024-elem) exclusive scan, block sums -> bsum
// ---------------------------------------------------------------------------
__global__ __launch_bounds__(256) void scan1_kernel(const int* __restrict__ in,
                                                    int* __restrict__ outp,
                                                    int* __restrict__ bsum, int n) {
    __shared__ int tmp[256];
    int t = threadIdx.x;
    int base = blockIdx.x * 1024;
    int v[4]; int s = 0;
    #pragma unroll
    for (int j = 0; j < 4; ++j) {
        int idx = base + t * 4 + j;
        v[j] = (idx < n) ? in[idx] : 0;
        s += v[j];
    }
    tmp[t] = s;
    __syncthreads();
    for (int off = 1; off < 256; off <<= 1) {
        int a = (t >= off) ? tmp[t - off] : 0;
        __syncthreads();
        tmp[t] += a;
        __syncthreads();
    }
    int excl = tmp[t] - s;
    if (t == 255) bsum[blockIdx.x] = tmp[255];
    int run = excl;
    #pragma unroll
    for (int j = 0; j < 4; ++j) {
        int idx = base + t * 4 + j;
        if (idx < n) outp[idx] = run;
        run += v[j];
    }
}

__global__ __launch_bounds__(128) void scan2_kernel(int* __restrict__ bsum, int nb) {
    __shared__ int tmp[128];
    int t = threadIdx.x;
    int v = (t < nb) ? bsum[t] : 0;
    tmp[t] = v;
    __syncthreads();
    for (int off = 1; off < 128; off <<= 1) {
        int a = (t >= off) ? tmp[t - off] : 0;
        __syncthreads();
        tmp[t] += a;
        __syncthreads();
    }
    if (t < nb) bsum[t] = tmp[t] - v;
}

__global__ void scan3_kernel(int* __restrict__ arr, const int* __restrict__ bsum, int n) {
    int i = blockIdx.x * blockDim.x + threadIdx.x;
    if (i < n) arr[i] += bsum[i >> 10];
}

// ---------------------------------------------------------------------------
// Phase C: partition edges into bucket regions (near-sequential per stream)
// ---------------------------------------------------------------------------
__global__ __launch_bounds__(256) void part_kernel(const int* __restrict__ ei,
                                                   const int* __restrict__ base,
                                                   int* __restrict__ srcbuf,
                                                   unsigned short* __restrict__ dstlbuf) {
    __shared__ int cur[NBUCK];
    int t = threadIdx.x, blk = blockIdx.x;
    cur[t] = base[t * NBLK_P + blk];
    __syncthreads();
    int e0 = blk * CHUNK;
    for (int i = t; i < CHUNK; i += 256) {
        int e = e0 + i;
        if (e >= N_EDGES) break;
        unsigned d = (unsigned)ei[N_EDGES + e];
        int s = ei[e];
        int b = __umulhi(d, MAGIC);
        int pos = atomicAdd(&cur[b], 1);
        srcbuf[pos] = s;
        dstlbuf[pos] = (unsigned short)(d - b * NPB);
    }
}

// ---------------------------------------------------------------------------
// Refine: one block per bucket; LDS counting sort by dst_local; coalesced
// csr_src write; emits rowptr from the local exclusive scan.
// ---------------------------------------------------------------------------
__global__ __launch_bounds__(256) void refine_kernel(const int* __restrict__ srcbuf,
                                                     const unsigned short* __restrict__ dstlbuf,
                                                     const int* __restrict__ base,
                                                     int* __restrict__ csr_src,
                                                     int* __restrict__ rowptr) {
    __shared__ int cnt[NPB + 1];
    __shared__ int cur[NPB + 1];
    __shared__ int tmp[256];
    __shared__ int outb[CAP];
    int t = threadIdx.x, b = blockIdx.x;
    int beg = base[b * NBLK_P];
    int end = (b == NBUCK - 1) ? N_EDGES : base[(b + 1) * NBLK_P];

    for (int i = t; i < NPB + 1; i += 256) cnt[i] = 0;
    __syncthreads();
    for (int i = beg + t; i < end; i += 256)
        atomicAdd(&cnt[dstlbuf[i]], 1);
    __syncthreads();

    int i0 = 2 * t, i1 = 2 * t + 1;
    int v0 = (i0 < NPB) ? cnt[i0] : 0;
    int v1 = (i1 < NPB) ? cnt[i1] : 0;
    int s = v0 + v1;
    tmp[t] = s;
    __syncthreads();
    for (int off = 1; off < 256; off <<= 1) {
        int a = (t >= off) ? tmp[t - off] : 0;
        __syncthreads();
        tmp[t] += a;
        __syncthreads();
    }
    int excl = tmp[t] - s;
    if (i0 < NPB) cur[i0] = excl;
    if (i1 < NPB) cur[i1] = excl + v0;
    {
        int g0 = b * NPB + i0;
        if (i0 < NPB && g0 < N_NODES) rowptr[g0] = beg + excl;
        int g1 = b * NPB + i1;
        if (i1 < NPB && g1 < N_NODES) rowptr[g1] = beg + excl + v0;
    }
    if (b == NBUCK - 1 && t == 0) rowptr[N_NODES] = N_EDGES;
    __syncthreads();

    for (int i = beg + t; i < end; i += 256) {
        int dl = dstlbuf[i];
        int pos = atomicAdd(&cur[dl], 1);
        if (pos < CAP) outb[pos] = srcbuf[i];
    }
    __syncthreads();

    int nb = end - beg; if (nb > CAP) nb = CAP;
    for (int i = t; i < nb; i += 256) csr_src[beg + i] = outb[i];
}

// ---------------------------------------------------------------------------
// In-register gather of one node row into MFMA A-frag accumulators.
// Thread (m,q) owns row r, k in [q*8, q*8+7] (acc[0..7]) and
// [32+q*8, 32+q*8+7] (acc[8..15]).
// ---------------------------------------------------------------------------
__device__ __forceinline__ void gather_row(const unsigned short* __restrict__ feat,
                                           const int* __restrict__ rowptr,
                                           const int* __restrict__ csr_src,
                                           int r, int q, float* acc) {
    const u16x8* f8 = (const u16x8*)feat;
    u16x8 v0 = f8[(long long)r * 8 + q];
    u16x8 v1 = f8[(long long)r * 8 + 4 + q];
    #pragma unroll
    for (int j = 0; j < 8; ++j) { acc[j] = bf2f(v0[j]); acc[8 + j] = bf2f(v1[j]); }
    int k = rowptr[r], end = rowptr[r + 1];
    int sn = (k < end) ? csr_src[k] : 0;
    while (k < end) {
        int sc = sn;
        ++k;
        if (k < end) sn = csr_src[k];
        u16x8 p0 = f8[(long long)sc * 8 + q];
        u16x8 p1 = f8[(long long)sc * 8 + 4 + q];
        #pragma unroll
        for (int j = 0; j < 8; ++j) { acc[j] += bf2f(p0[j]); acc[8 + j] += bf2f(p1[j]); }
    }
}

__device__ __forceinline__ void pack_frags(const float* acc, bfx8& a0, bfx8& a1) {
    #pragma unroll
    for (int j = 0; j < 8; ++j) {
        a0[j] = (short)f2bf(acc[j]);
        a1[j] = (short)f2bf(acc[8 + j]);
    }
}

// ---------------------------------------------------------------------------
// Fused gather + conv1 MLP:
//   h0 = gather(xbf); h1 = relu(bn1(h0 @ W1a + b1a)); h2 = relu(h1 @ W1b + b1b)
// Weights pre-packed transposed bf16: frag = one 16B vector load.
// ---------------------------------------------------------------------------
__global__ __launch_bounds__(256) void gmlp1_kernel(
    const unsigned short* __restrict__ feat,
    const int* __restrict__ rowptr, const int* __restrict__ csr_src,
    const unsigned short* __restrict__ wpA, const unsigned short* __restrict__ wpB,
    const float* __restrict__ s1, const float* __restrict__ o1,
    const float* __restrict__ b1b,
    unsigned short* __restrict__ h2) {
    __shared__ unsigned short h1t[4][16 * 72];   // stride 72 (144B, 16B-aligned)
    __shared__ unsigned short outt[4][16 * 64];

    int t = threadIdx.x;
    int w = t >> 6, lane = t & 63;
    int m = lane & 15, q = lane >> 4;
    int row0 = blockIdx.x * 64 + w * 16;

    int r = row0 + m;
    if (r > N_NODES - 1) r = N_NODES - 1;

    float accg[16];
    gather_row(feat, rowptr, csr_src, r, q, accg);
    bfx8 a0, a1;
    pack_frags(accg, a0, a1);

    const bfx8* wA8 = (const bfx8*)wpA;
    const bfx8* wB8 = (const bfx8*)wpB;

    float A1[4], B1[4], B2c[4];
    #pragma unroll
    for (int nt = 0; nt < 4; ++nt) {
        int c = nt * 16 + m;
        A1[nt] = s1[c];
        B1[nt] = o1[c];
        B2c[nt] = b1b[c];
    }

    // layer 1
    f32x4 acc[4];
    #pragma unroll
    for (int nt = 0; nt < 4; ++nt) {
        int cb = (nt * 16 + m) * 8;
        acc[nt] = (f32x4){0.f, 0.f, 0.f, 0.f};
        acc[nt] = __builtin_amdgcn_mfma_f32_16x16x32_bf16(a0, wA8[cb + q], acc[nt], 0, 0, 0);
        acc[nt] = __builtin_amdgcn_mfma_f32_16x16x32_bf16(a1, wA8[cb + 4 + q], acc[nt], 0, 0, 0);
    }
    #pragma unroll
    for (int nt = 0; nt < 4; ++nt)
        #pragma unroll
        for (int rr = 0; rr < 4; ++rr) {
            float v = fmaxf(acc[nt][rr] * A1[nt] + B1[nt], 0.f);
            h1t[w][(q * 4 + rr) * 72 + nt * 16 + m] = f2bf(v);
        }
    __syncthreads();

    // layer 2
    const bfx8* hp = (const bfx8*)&h1t[w][m * 72];
    bfx8 c0 = hp[q];
    bfx8 c1 = hp[4 + q];
    f32x4 acc2[4];
    #pragma unroll
    for (int nt = 0; nt < 4; ++nt) {
        int cb = (nt * 16 + m) * 8;
        acc2[nt] = (f32x4){0.f, 0.f, 0.f, 0.f};
        acc2[nt] = __builtin_amdgcn_mfma_f32_16x16x32_bf16(c0, wB8[cb + q], acc2[nt], 0, 0, 0);
        acc2[nt] = __builtin_amdgcn_mfma_f32_16x16x32_bf16(c1, wB8[cb + 4 + q], acc2[nt], 0, 0, 0);
    }
    #pragma unroll
    for (int nt = 0; nt < 4; ++nt)
        #pragma unroll
        for (int rr = 0; rr < 4; ++rr) {
            float v = fmaxf(acc2[nt][rr] + B2c[nt], 0.f);
            outt[w][(q * 4 + rr) * 64 + nt * 16 + m] = f2bf(v);
        }
    __syncthreads();

    #pragma unroll
    for (int i = lane; i < 128; i += 64) {
        int rr = i >> 3, cc = i & 7;
        int rg = row0 + rr;
        if (rg < N_NODES)
            ((float4*)h2)[(long long)rg * 8 + cc] = *(const float4*)&outt[w][rr * 64 + cc * 8];
    }
}

// ---------------------------------------------------------------------------
// Fused gather + conv2 + pool:
//   h3 = gather(h2); h4 = relu(bn2(h3 @ W2 + b2)); xs[batch[row]] += h4
// ---------------------------------------------------------------------------
__global__ __launch_bounds__(256) void gmlp2_kernel(
    const unsigned short* __restrict__ feat,
    const int* __restrict__ rowptr, const int* __restrict__ csr_src,
    const unsigned short* __restrict__ wpC,
    const float* __restrict__ s2, const float* __restrict__ o2,
    const int* __restrict__ batch,
    float* __restrict__ xs) {
    __shared__ float pool[64 * 64];
    __shared__ int bts[64];

    int t = threadIdx.x;
    int w = t >> 6, lane = t & 63;
    int m = lane & 15, q = lane >> 4;
    int row0b = blockIdx.x * 64;
    int row0 = row0b + w * 16;

    if (t < 64) {
        int rg = row0b + t;
        bts[t] = (rg < N_NODES) ? batch[rg] : -1;
    }

    int r = row0 + m;
    if (r > N_NODES - 1) r = N_NODES - 1;

    float accg[16];
    gather_row(feat, rowptr, csr_src, r, q, accg);
    bfx8 a0, a1;
    pack_frags(accg, a0, a1);

    const bfx8* wC8 = (const bfx8*)wpC;
    float A[4], Bc[4];
    #pragma unroll
    for (int nt = 0; nt < 4; ++nt) {
        int c = nt * 16 + m;
        A[nt] = s2[c];
        Bc[nt] = o2[c];
    }

    f32x4 acc[4];
    #pragma unroll
    for (int nt = 0; nt < 4; ++nt) {
        int cb = (nt * 16 + m) * 8;
        acc[nt] = (f32x4){0.f, 0.f, 0.f, 0.f};
        acc[nt] = __builtin_amdgcn_mfma_f32_16x16x32_bf16(a0, wC8[cb + q], acc[nt], 0, 0, 0);
        acc[nt] = __builtin_amdgcn_mfma_f32_16x16x32_bf16(a1, wC8[cb + 4 + q], acc[nt], 0, 0, 0);
    }
    #pragma unroll
    for (int nt = 0; nt < 4; ++nt)
        #pragma unroll
        for (int rr = 0; rr < 4; ++rr) {
            float v = fmaxf(acc[nt][rr] * A[nt] + Bc[nt], 0.f);
            pool[(w * 16 + q * 4 + rr) * 64 + nt * 16 + m] = v;
        }
    __syncthreads();

    int col = t & 63;
    int r0 = (t >> 6) * 16;
    int cb = bts[r0];
    float cur = 0.f;
    #pragma unroll
    for (int rr = 0; rr < 16; ++rr) {
        int b = bts[r0 + rr];
        if (b != cb) {
            if (cb >= 0) unsafeAtomicAdd(&xs[cb * 64 + col], cur);
            cb = b;
            cur = 0.f;
        }
        cur += pool[(r0 + rr) * 64 + col];
    }
    if (cb >= 0) unsafeAtomicAdd(&xs[cb * 64 + col], cur);
}

// ---------------------------------------------------------------------------
// Head: x_topo = relu(topo @ Wt + bt); out = [x_struct, x_topo] @ Wc + bc
// ---------------------------------------------------------------------------
__global__ __launch_bounds__(64) void head_kernel(
    const float* __restrict__ xs, const float* __restrict__ topo,
    const float* __restrict__ Wt, const float* __restrict__ bt,
    const float* __restrict__ Wc, const float* __restrict__ bc,
    float* __restrict__ out) {
    __shared__ float trow[64];
    __shared__ float comb[128];
    int b = blockIdx.x;
    int h = threadIdx.x;
    trow[h] = topo[b * 64 + h];
    __syncthreads();
    float acc = bt[h];
    #pragma unroll
    for (int k = 0; k < 64; ++k) acc += trow[k] * Wt[k * 64 + h];
    comb[h] = xs[b * 64 + h];
    comb[64 + h] = fmaxf(acc, 0.f);
    __syncthreads();
    if (h < NCLASS) {
        float o = bc[h];
        #pragma unroll
        for (int k = 0; k < 128; ++k) o += comb[k] * Wc[k * NCLASS + h];
        out[b * NCLASS + h] = o;
    }
}

// ---------------------------------------------------------------------------
extern "C" void kernel_launch(void* const* d_in, const int* in_sizes, int n_in,
                              void* d_out, int out_size, void* d_ws, size_t ws_size,
                              hipStream_t stream) {
    const float* x     = (const float*)d_in[0];
    const int*   ei    = (const int*)d_in[1];
    const int*   batch = (const int*)d_in[2];
    const float* topo  = (const float*)d_in[3];
    const float* W1a   = (const float*)d_in[4];
    const float* b1a   = (const float*)d_in[5];
    const float* g1    = (const float*)d_in[6];
    const float* be1   = (const float*)d_in[7];
    const float* m1    = (const float*)d_in[8];
    const float* v1    = (const float*)d_in[9];
    const float* W1b   = (const float*)d_in[10];
    const float* b1b   = (const float*)d_in[11];
    const float* W2    = (const float*)d_in[12];
    const float* b2    = (const float*)d_in[13];
    const float* g2    = (const float*)d_in[14];
    const float* be2   = (const float*)d_in[15];
    const float* m2    = (const float*)d_in[16];
    const float* v2    = (const float*)d_in[17];
    const float* Wt    = (const float*)d_in[18];
    const float* bt    = (const float*)d_in[19];
    const float* Wc    = (const float*)d_in[20];
    const float* bc    = (const float*)d_in[21];
    float* out = (float*)d_out;

    // Workspace layout (16B-aligned chunks)
    char* p = (char*)d_ws;
    unsigned short* xbf  = (unsigned short*)p; p += (size_t)N_NODES * DIM * 2;  // 12.8 MB
    unsigned short* bufB = (unsigned short*)p; p += (size_t)N_NODES * DIM * 2;  // 12.8 MB (h2)
    float* xs      = (float*)p; p += (size_t)BGRAPHS * DIM * 4;                 // 256 KB
    int*   rowptr  = (int*)p;   p += (size_t)(N_NODES + 16) * 4;                // 400 KB
    int*   histc   = (int*)p;   p += (size_t)SCAN_N * 4;                        // 150 KB
    int*   base    = (int*)p;   p += (size_t)SCAN_N * 4;                        // 150 KB
    int*   bsum    = (int*)p;   p += 256 * 4;
    int*   srcbuf  = (int*)p;   p += (size_t)N_EDGES * 4;                       // 4.8 MB
    unsigned short* dstlbuf = (unsigned short*)p; p += (size_t)N_EDGES * 2;     // 2.4 MB
    int*   csr_src = (int*)p;   p += (size_t)N_EDGES * 4;                       // 4.8 MB
    unsigned short* wpA = (unsigned short*)p; p += 4096 * 2;
    unsigned short* wpB = (unsigned short*)p; p += 4096 * 2;
    unsigned short* wpC = (unsigned short*)p; p += 4096 * 2;
    float* s1 = (float*)p; p += 64 * 4;
    float* o1 = (float*)p; p += 64 * 4;
    float* s2 = (float*)p; p += 64 * 4;
    float* o2 = (float*)p; p += 64 * 4;

    const int NB_C  = (N_NODES * DIM / 8 + 255) / 256;   // 3125
    const int NB_S1 = (SCAN_N + 1023) / 1024;            // 37
    const int NB_S3 = (SCAN_N + 255) / 256;              // 147

    convert_kernel<<<NB_C, 256, 0, stream>>>(x, xbf, xs);
    prep_kernel<<<48, 256, 0, stream>>>(W1a, W1b, W2, b1a, g1, be1, m1, v1,
                                        b2, g2, be2, m2, v2,
                                        wpA, wpB, wpC, s1, o1, s2, o2);
    histA_kernel<<<NBLK_P, 256, 0, stream>>>(ei, histc);
    scan1_kernel<<<NB_S1, 256, 0, stream>>>(histc, base, bsum, SCAN_N);
    scan2_kernel<<<1, 128, 0, stream>>>(bsum, NB_S1);
    scan3_kernel<<<NB_S3, 256, 0, stream>>>(base, bsum, SCAN_N);
    part_kernel<<<NBLK_P, 256, 0, stream>>>(ei, base, srcbuf, dstlbuf);
    refine_kernel<<<NBUCK, 256, 0, stream>>>(srcbuf, dstlbuf, base, csr_src, rowptr);

    // fused gather + conv1 MLP: bufB = h2 (bf16)
    gmlp1_kernel<<<(N_NODES + 63) / 64, 256, 0, stream>>>(
        xbf, rowptr, csr_src, wpA, wpB, s1, o1, b1b, bufB);
    // fused gather + conv2 + pool
    gmlp2_kernel<<<(N_NODES + 63) / 64, 256, 0, stream>>>(
        bufB, rowptr, csr_src, wpC, s2, o2, batch, xs);
    // head
    head_kernel<<<BGRAPHS, 64, 0, stream>>>(xs, topo, Wt, bt, Wc, bc, out);
}

// Round 6
// 260.834 us; speedup vs baseline: 1.0083x; 1.0083x over previous
//
#include <hip/hip_runtime.h>

// Problem constants (match reference)
#define N_NODES 100000
#define N_EDGES 1200000
#define DIM     64
#define BGRAPHS 1000
#define NCLASS  10
#define BN_EPS  1e-5f

// CSR-build partition constants
#define NBUCK   256            // coarse buckets
#define NPB     391            // nodes per bucket (256*391 = 100096 >= N)
#define MAGIC   10984572u      // ceil(2^32/391): bucket = umulhi(d, MAGIC)
#define CHUNK   8192           // edges per partition block
#define NBLK_P  147            // ceil(E / CHUNK)
#define CAP     8192           // refine LDS staging capacity (>= max bucket edges)
#define NB_C    3125           // convert blocks: N*DIM/8/256

typedef __attribute__((ext_vector_type(8))) short   bfx8;   // 8 bf16 MFMA A/B frag
typedef __attribute__((ext_vector_type(4))) float   f32x4;  // MFMA C/D frag
typedef __attribute__((ext_vector_type(8))) unsigned short u16x8;

__device__ __forceinline__ unsigned short f2bf(float f) {
    unsigned u = __builtin_bit_cast(unsigned, f);
    unsigned r = (u + 0x7FFFu + ((u >> 16) & 1u)) >> 16;   // RNE
    return (unsigned short)r;
}
__device__ __forceinline__ float bf2f(unsigned short h) {
    unsigned u = ((unsigned)h) << 16;
    return __builtin_bit_cast(float, u);
}

// ---------------------------------------------------------------------------
// Setup (one launch, three block-ranges):
//  [0, NB_C)            : x fp32->bf16, zero xs
//  [NB_C, NB_C+NBLK_P)  : per-chunk bucket histogram -> histc[bucket*NBLK_P+blk]
//  last block           : pack W1a/W1b/W2 transposed bf16 + fold BN
// ---------------------------------------------------------------------------
__global__ __launch_bounds__(256) void setup_kernel(
    const float* __restrict__ x, unsigned short* __restrict__ xbf, float* __restrict__ xs,
    const int* __restrict__ ei, int* __restrict__ histc,
    const float* __restrict__ W1a, const float* __restrict__ W1b, const float* __restrict__ W2,
    const float* __restrict__ b1a,
    const float* __restrict__ g1, const float* __restrict__ be1,
    const float* __restrict__ m1, const float* __restrict__ v1,
    const float* __restrict__ b2,
    const float* __restrict__ g2, const float* __restrict__ be2,
    const float* __restrict__ m2, const float* __restrict__ v2,
    unsigned short* __restrict__ wpA, unsigned short* __restrict__ wpB,
    unsigned short* __restrict__ wpC,
    float* __restrict__ s1, float* __restrict__ o1,
    float* __restrict__ s2, float* __restrict__ o2) {
    int blk = blockIdx.x, t = threadIdx.x;
    if (blk < NB_C) {
        int i = blk * 256 + t;              // < 800000 exactly
        float4 a = ((const float4*)x)[i * 2];
        float4 b = ((const float4*)x)[i * 2 + 1];
        u16x8 o;
        o[0] = f2bf(a.x); o[1] = f2bf(a.y); o[2] = f2bf(a.z); o[3] = f2bf(a.w);
        o[4] = f2bf(b.x); o[5] = f2bf(b.y); o[6] = f2bf(b.z); o[7] = f2bf(b.w);
        ((u16x8*)xbf)[i] = o;
        if (i < BGRAPHS * DIM) xs[i] = 0.f;
        return;
    }
    blk -= NB_C;
    if (blk < NBLK_P) {
        __shared__ int cnt[NBUCK];
        cnt[t] = 0;
        __syncthreads();
        int e0 = blk * CHUNK;
        int eend = e0 + CHUNK; if (eend > N_EDGES) eend = N_EDGES;
        for (int e = e0 + t; e < eend; e += 256) {
            unsigned d = (unsigned)ei[N_EDGES + e];
            atomicAdd(&cnt[__umulhi(d, MAGIC)], 1);
        }
        __syncthreads();
        histc[t * NBLK_P + blk] = cnt[t];
        return;
    }
    // weights + BN fold (single block)
    for (int i = t; i < 3 * 4096; i += 256) {
        int mat = i >> 12, j = i & 4095;
        int col = j >> 6, k = j & 63;
        const float* W = (mat == 0) ? W1a : ((mat == 1) ? W1b : W2);
        unsigned short* wp = (mat == 0) ? wpA : ((mat == 1) ? wpB : wpC);
        wp[j] = f2bf(W[k * 64 + col]);
    }
    if (t < 64) {
        float s = g1[t] * rsqrtf(v1[t] + BN_EPS);
        s1[t] = s;
        o1[t] = b1a[t] * s + (be1[t] - m1[t] * s);
        float sv = g2[t] * rsqrtf(v2[t] + BN_EPS);
        s2[t] = sv;
        o2[t] = b2[t] * sv + (be2[t] - m2[t] * sv);
    }
}

// ---------------------------------------------------------------------------
// scanS: one block; total per bucket = sum of histc row; exclusive scan ->
// base[257]; cursor = base.
// ---------------------------------------------------------------------------
__global__ __launch_bounds__(256) void scanS_kernel(const int* __restrict__ histc,
                                                    int* __restrict__ base,
                                                    int* __restrict__ cursor) {
    __shared__ int tmp[256];
    int t = threadIdx.x;
    int s = 0;
    for (int i = 0; i < NBLK_P; ++i) s += histc[t * NBLK_P + i];
    tmp[t] = s;
    __syncthreads();
    for (int off = 1; off < 256; off <<= 1) {
        int a = (t >= off) ? tmp[t - off] : 0;
        __syncthreads();
        tmp[t] += a;
        __syncthreads();
    }
    int excl = tmp[t] - s;
    base[t] = excl;
    cursor[t] = excl;
    if (t == 255) base[256] = N_EDGES;
}

// ---------------------------------------------------------------------------
// part: per-block LDS histogram -> reserve contiguous ranges via global
// bucket cursors -> scatter (src, dst_local) into bucket regions.
// ---------------------------------------------------------------------------
__global__ __launch_bounds__(256) void part_kernel(const int* __restrict__ ei,
                                                   int* __restrict__ cursor,
                                                   int* __restrict__ srcbuf,
                                                   unsigned short* __restrict__ dstlbuf) {
    __shared__ int cnt[NBUCK];
    __shared__ int cur[NBUCK];
    int t = threadIdx.x, blk = blockIdx.x;
    cnt[t] = 0;
    __syncthreads();
    int e0 = blk * CHUNK;
    int eend = e0 + CHUNK; if (eend > N_EDGES) eend = N_EDGES;
    for (int e = e0 + t; e < eend; e += 256) {
        unsigned d = (unsigned)ei[N_EDGES + e];
        atomicAdd(&cnt[__umulhi(d, MAGIC)], 1);
    }
    __syncthreads();
    int c = cnt[t];
    cur[t] = (c > 0) ? atomicAdd(&cursor[t], c) : 0;
    __syncthreads();
    for (int e = e0 + t; e < eend; e += 256) {
        unsigned d = (unsigned)ei[N_EDGES + e];
        int s = ei[e];
        int b = __umulhi(d, MAGIC);
        int pos = atomicAdd(&cur[b], 1);
        srcbuf[pos] = s;
        dstlbuf[pos] = (unsigned short)(d - b * NPB);
    }
}

// ---------------------------------------------------------------------------
// refine: one block per bucket; LDS counting sort by dst_local; coalesced
// csr_src write; emits rowptr from the local exclusive scan.
// ---------------------------------------------------------------------------
__global__ __launch_bounds__(256) void refine_kernel(const int* __restrict__ srcbuf,
                                                     const unsigned short* __restrict__ dstlbuf,
                                                     const int* __restrict__ base,
                                                     int* __restrict__ csr_src,
                                                     int* __restrict__ rowptr) {
    __shared__ int cnt[NPB + 1];
    __shared__ int cur[NPB + 1];
    __shared__ int tmp[256];
    __shared__ int outb[CAP];
    int t = threadIdx.x, b = blockIdx.x;
    int beg = base[b];
    int end = base[b + 1];

    for (int i = t; i < NPB + 1; i += 256) cnt[i] = 0;
    __syncthreads();
    for (int i = beg + t; i < end; i += 256)
        atomicAdd(&cnt[dstlbuf[i]], 1);
    __syncthreads();

    int i0 = 2 * t, i1 = 2 * t + 1;
    int v0 = (i0 < NPB) ? cnt[i0] : 0;
    int v1 = (i1 < NPB) ? cnt[i1] : 0;
    int s = v0 + v1;
    tmp[t] = s;
    __syncthreads();
    for (int off = 1; off < 256; off <<= 1) {
        int a = (t >= off) ? tmp[t - off] : 0;
        __syncthreads();
        tmp[t] += a;
        __syncthreads();
    }
    int excl = tmp[t] - s;
    if (i0 < NPB) cur[i0] = excl;
    if (i1 < NPB) cur[i1] = excl + v0;
    {
        int g0 = b * NPB + i0;
        if (i0 < NPB && g0 < N_NODES) rowptr[g0] = beg + excl;
        int g1 = b * NPB + i1;
        if (i1 < NPB && g1 < N_NODES) rowptr[g1] = beg + excl + v0;
    }
    if (b == NBUCK - 1 && t == 0) rowptr[N_NODES] = N_EDGES;
    __syncthreads();

    for (int i = beg + t; i < end; i += 256) {
        int dl = dstlbuf[i];
        int pos = atomicAdd(&cur[dl], 1);
        if (pos < CAP) outb[pos] = srcbuf[i];
    }
    __syncthreads();

    int nb = end - beg; if (nb > CAP) nb = CAP;
    for (int i = t; i < nb; i += 256) csr_src[beg + i] = outb[i];
}

// ---------------------------------------------------------------------------
// bf16 gather: out[i] = feat[i] + sum_{s in nbrs(i)} feat[s]
// 8 lanes/node (16B/lane), 32 nodes per block; neighbor loop unrolled x4
// for memory-level parallelism (4 independent row loads in flight).
// ---------------------------------------------------------------------------
__global__ __launch_bounds__(256) void gather_kernel(const unsigned short* __restrict__ feat,
                                                     const int* __restrict__ rowptr,
                                                     const int* __restrict__ csr_src,
                                                     unsigned short* __restrict__ out) {
    int t = threadIdx.x;
    int node = blockIdx.x * 32 + (t >> 3);
    int q = t & 7;
    if (node >= N_NODES) return;
    const u16x8* f8 = (const u16x8*)feat;
    u16x8 sv = f8[(long long)node * 8 + q];
    float acc[8];
    #pragma unroll
    for (int j = 0; j < 8; ++j) acc[j] = bf2f(sv[j]);
    int k = rowptr[node], end = rowptr[node + 1];
    for (; k + 4 <= end; k += 4) {
        int s0 = csr_src[k], s1 = csr_src[k + 1], s2 = csr_src[k + 2], s3 = csr_src[k + 3];
        u16x8 v0 = f8[(long long)s0 * 8 + q];
        u16x8 v1 = f8[(long long)s1 * 8 + q];
        u16x8 v2 = f8[(long long)s2 * 8 + q];
        u16x8 v3 = f8[(long long)s3 * 8 + q];
        #pragma unroll
        for (int j = 0; j < 8; ++j)
            acc[j] += (bf2f(v0[j]) + bf2f(v1[j])) + (bf2f(v2[j]) + bf2f(v3[j]));
    }
    for (; k < end; ++k) {
        int sc = csr_src[k];
        u16x8 v = f8[(long long)sc * 8 + q];
        #pragma unroll
        for (int j = 0; j < 8; ++j) acc[j] += bf2f(v[j]);
    }
    u16x8 o;
    #pragma unroll
    for (int j = 0; j < 8; ++j) o[j] = f2bf(acc[j]);
    ((u16x8*)out)[(long long)node * 8 + q] = o;
}

// ---------------------------------------------------------------------------
// MFMA conv1 MLP (packed bf16 weights, folded BN):
//   h2 = relu(relu(bn1(h0 @ W1a)) @ W1b + b1b)
// ---------------------------------------------------------------------------
__global__ __launch_bounds__(256) void mlp1_kernel(
    const unsigned short* __restrict__ h0,
    const unsigned short* __restrict__ wpA, const unsigned short* __restrict__ wpB,
    const float* __restrict__ s1, const float* __restrict__ o1,
    const float* __restrict__ b1b,
    unsigned short* __restrict__ h2) {
    __shared__ unsigned short h1t[4][16 * 72];   // stride 72 (144B, 16B-aligned)
    __shared__ unsigned short outt[4][16 * 64];

    int t = threadIdx.x;
    int w = t >> 6, lane = t & 63;
    int m = lane & 15, q = lane >> 4;
    int row0 = blockIdx.x * 64 + w * 16;

    int r = row0 + m;
    if (r > N_NODES - 1) r = N_NODES - 1;
    const bfx8* ap = (const bfx8*)(h0 + (long long)r * 64);
    bfx8 a0 = ap[q];
    bfx8 a1 = ap[4 + q];

    const bfx8* wA8 = (const bfx8*)wpA;
    const bfx8* wB8 = (const bfx8*)wpB;

    float A1[4], B1[4], B2c[4];
    #pragma unroll
    for (int nt = 0; nt < 4; ++nt) {
        int c = nt * 16 + m;
        A1[nt] = s1[c];
        B1[nt] = o1[c];
        B2c[nt] = b1b[c];
    }

    f32x4 acc[4];
    #pragma unroll
    for (int nt = 0; nt < 4; ++nt) {
        int cb = (nt * 16 + m) * 8;
        acc[nt] = (f32x4){0.f, 0.f, 0.f, 0.f};
        acc[nt] = __builtin_amdgcn_mfma_f32_16x16x32_bf16(a0, wA8[cb + q], acc[nt], 0, 0, 0);
        acc[nt] = __builtin_amdgcn_mfma_f32_16x16x32_bf16(a1, wA8[cb + 4 + q], acc[nt], 0, 0, 0);
    }
    #pragma unroll
    for (int nt = 0; nt < 4; ++nt)
        #pragma unroll
        for (int rr = 0; rr < 4; ++rr) {
            float v = fmaxf(acc[nt][rr] * A1[nt] + B1[nt], 0.f);
            h1t[w][(q * 4 + rr) * 72 + nt * 16 + m] = f2bf(v);
        }
    __syncthreads();

    const bfx8* hp = (const bfx8*)&h1t[w][m * 72];
    bfx8 c0 = hp[q];
    bfx8 c1 = hp[4 + q];
    f32x4 acc2[4];
    #pragma unroll
    for (int nt = 0; nt < 4; ++nt) {
        int cb = (nt * 16 + m) * 8;
        acc2[nt] = (f32x4){0.f, 0.f, 0.f, 0.f};
        acc2[nt] = __builtin_amdgcn_mfma_f32_16x16x32_bf16(c0, wB8[cb + q], acc2[nt], 0, 0, 0);
        acc2[nt] = __builtin_amdgcn_mfma_f32_16x16x32_bf16(c1, wB8[cb + 4 + q], acc2[nt], 0, 0, 0);
    }
    #pragma unroll
    for (int nt = 0; nt < 4; ++nt)
        #pragma unroll
        for (int rr = 0; rr < 4; ++rr) {
            float v = fmaxf(acc2[nt][rr] + B2c[nt], 0.f);
            outt[w][(q * 4 + rr) * 64 + nt * 16 + m] = f2bf(v);
        }
    __syncthreads();

    #pragma unroll
    for (int i = lane; i < 128; i += 64) {
        int rr = i >> 3, cc = i & 7;
        int rg = row0 + rr;
        if (rg < N_NODES)
            ((float4*)h2)[(long long)rg * 8 + cc] = *(const float4*)&outt[w][rr * 64 + cc * 8];
    }
}

// ---------------------------------------------------------------------------
// MFMA conv2 + pool: h4 = relu(bn2(h3 @ W2)); xs[batch[row]] += h4
// ---------------------------------------------------------------------------
__global__ __launch_bounds__(256) void mlp2_kernel(
    const unsigned short* __restrict__ h3,
    const unsigned short* __restrict__ wpC,
    const float* __restrict__ s2, const float* __restrict__ o2,
    const int* __restrict__ batch,
    float* __restrict__ xs) {
    __shared__ float pool[64 * 64];
    __shared__ int bts[64];

    int t = threadIdx.x;
    int w = t >> 6, lane = t & 63;
    int m = lane & 15, q = lane >> 4;
    int row0b = blockIdx.x * 64;
    int row0 = row0b + w * 16;

    if (t < 64) {
        int rg = row0b + t;
        bts[t] = (rg < N_NODES) ? batch[rg] : -1;
    }

    int r = row0 + m;
    if (r > N_NODES - 1) r = N_NODES - 1;
    const bfx8* ap = (const bfx8*)(h3 + (long long)r * 64);
    bfx8 a0 = ap[q];
    bfx8 a1 = ap[4 + q];

    const bfx8* wC8 = (const bfx8*)wpC;
    float A[4], Bc[4];
    #pragma unroll
    for (int nt = 0; nt < 4; ++nt) {
        int c = nt * 16 + m;
        A[nt] = s2[c];
        Bc[nt] = o2[c];
    }

    f32x4 acc[4];
    #pragma unroll
    for (int nt = 0; nt < 4; ++nt) {
        int cb = (nt * 16 + m) * 8;
        acc[nt] = (f32x4){0.f, 0.f, 0.f, 0.f};
        acc[nt] = __builtin_amdgcn_mfma_f32_16x16x32_bf16(a0, wC8[cb + q], acc[nt], 0, 0, 0);
        acc[nt] = __builtin_amdgcn_mfma_f32_16x16x32_bf16(a1, wC8[cb + 4 + q], acc[nt], 0, 0, 0);
    }
    #pragma unroll
    for (int nt = 0; nt < 4; ++nt)
        #pragma unroll
        for (int rr = 0; rr < 4; ++rr) {
            float v = fmaxf(acc[nt][rr] * A[nt] + Bc[nt], 0.f);
            pool[(w * 16 + q * 4 + rr) * 64 + nt * 16 + m] = v;
        }
    __syncthreads();

    int col = t & 63;
    int r0 = (t >> 6) * 16;
    int cb = bts[r0];
    float cur = 0.f;
    #pragma unroll
    for (int rr = 0; rr < 16; ++rr) {
        int b = bts[r0 + rr];
        if (b != cb) {
            if (cb >= 0) unsafeAtomicAdd(&xs[cb * 64 + col], cur);
            cb = b;
            cur = 0.f;
        }
        cur += pool[(r0 + rr) * 64 + col];
    }
    if (cb >= 0) unsafeAtomicAdd(&xs[cb * 64 + col], cur);
}

// ---------------------------------------------------------------------------
// Head: x_topo = relu(topo @ Wt + bt); out = [x_struct, x_topo] @ Wc + bc
// ---------------------------------------------------------------------------
__global__ __launch_bounds__(64) void head_kernel(
    const float* __restrict__ xs, const float* __restrict__ topo,
    const float* __restrict__ Wt, const float* __restrict__ bt,
    const float* __restrict__ Wc, const float* __restrict__ bc,
    float* __restrict__ out) {
    __shared__ float trow[64];
    __shared__ float comb[128];
    int b = blockIdx.x;
    int h = threadIdx.x;
    trow[h] = topo[b * 64 + h];
    __syncthreads();
    float acc = bt[h];
    #pragma unroll
    for (int k = 0; k < 64; ++k) acc += trow[k] * Wt[k * 64 + h];
    comb[h] = xs[b * 64 + h];
    comb[64 + h] = fmaxf(acc, 0.f);
    __syncthreads();
    if (h < NCLASS) {
        float o = bc[h];
        #pragma unroll
        for (int k = 0; k < 128; ++k) o += comb[k] * Wc[k * NCLASS + h];
        out[b * NCLASS + h] = o;
    }
}

// ---------------------------------------------------------------------------
extern "C" void kernel_launch(void* const* d_in, const int* in_sizes, int n_in,
                              void* d_out, int out_size, void* d_ws, size_t ws_size,
                              hipStream_t stream) {
    const float* x     = (const float*)d_in[0];
    const int*   ei    = (const int*)d_in[1];
    const int*   batch = (const int*)d_in[2];
    const float* topo  = (const float*)d_in[3];
    const float* W1a   = (const float*)d_in[4];
    const float* b1a   = (const float*)d_in[5];
    const float* g1    = (const float*)d_in[6];
    const float* be1   = (const float*)d_in[7];
    const float* m1    = (const float*)d_in[8];
    const float* v1    = (const float*)d_in[9];
    const float* W1b   = (const float*)d_in[10];
    const float* b1b   = (const float*)d_in[11];
    const float* W2    = (const float*)d_in[12];
    const float* b2    = (const float*)d_in[13];
    const float* g2    = (const float*)d_in[14];
    const float* be2   = (const float*)d_in[15];
    const float* m2    = (const float*)d_in[16];
    const float* v2    = (const float*)d_in[17];
    const float* Wt    = (const float*)d_in[18];
    const float* bt    = (const float*)d_in[19];
    const float* Wc    = (const float*)d_in[20];
    const float* bc    = (const float*)d_in[21];
    float* out = (float*)d_out;

    // Workspace layout (16B-aligned chunks)
    char* p = (char*)d_ws;
    unsigned short* xbf  = (unsigned short*)p; p += (size_t)N_NODES * DIM * 2;  // 12.8 MB
    unsigned short* bufA = (unsigned short*)p; p += (size_t)N_NODES * DIM * 2;  // 12.8 MB
    unsigned short* bufB = (unsigned short*)p; p += (size_t)N_NODES * DIM * 2;  // 12.8 MB
    float* xs      = (float*)p; p += (size_t)BGRAPHS * DIM * 4;                 // 256 KB
    int*   rowptr  = (int*)p;   p += (size_t)(N_NODES + 16) * 4;                // 400 KB
    int*   histc   = (int*)p;   p += (size_t)(NBUCK * NBLK_P + 16) * 4;         // 150 KB
    int*   base    = (int*)p;   p += (size_t)(NBUCK + 16) * 4;
    int*   cursor  = (int*)p;   p += (size_t)(NBUCK + 16) * 4;
    int*   srcbuf  = (int*)p;   p += (size_t)N_EDGES * 4;                       // 4.8 MB
    unsigned short* dstlbuf = (unsigned short*)p; p += (size_t)N_EDGES * 2;     // 2.4 MB
    int*   csr_src = (int*)p;   p += (size_t)N_EDGES * 4;                       // 4.8 MB
    unsigned short* wpA = (unsigned short*)p; p += 4096 * 2;
    unsigned short* wpB = (unsigned short*)p; p += 4096 * 2;
    unsigned short* wpC = (unsigned short*)p; p += 4096 * 2;
    float* s1 = (float*)p; p += 64 * 4;
    float* o1 = (float*)p; p += 64 * 4;
    float* s2 = (float*)p; p += 64 * 4;
    float* o2 = (float*)p; p += 64 * 4;

    setup_kernel<<<NB_C + NBLK_P + 1, 256, 0, stream>>>(
        x, xbf, xs, ei, histc,
        W1a, W1b, W2, b1a, g1, be1, m1, v1, b2, g2, be2, m2, v2,
        wpA, wpB, wpC, s1, o1, s2, o2);
    scanS_kernel<<<1, 256, 0, stream>>>(histc, base, cursor);
    part_kernel<<<NBLK_P, 256, 0, stream>>>(ei, cursor, srcbuf, dstlbuf);
    refine_kernel<<<NBUCK, 256, 0, stream>>>(srcbuf, dstlbuf, base, csr_src, rowptr);

    // agg1: bufA = xbf + scatter(xbf)
    gather_kernel<<<(N_NODES + 31) / 32, 256, 0, stream>>>(xbf, rowptr, csr_src, bufA);
    // conv1 MLP (MFMA, packed weights): bufB = h2
    mlp1_kernel<<<(N_NODES + 63) / 64, 256, 0, stream>>>(
        bufA, wpA, wpB, s1, o1, b1b, bufB);
    // agg2: bufA = h2 + scatter(h2)
    gather_kernel<<<(N_NODES + 31) / 32, 256, 0, stream>>>(bufB, rowptr, csr_src, bufA);
    // conv2 + pool (MFMA)
    mlp2_kernel<<<(N_NODES + 63) / 64, 256, 0, stream>>>(
        bufA, wpC, s2, o2, batch, xs);
    // head
    head_kernel<<<BGRAPHS, 64, 0, stream>>>(xs, topo, Wt, bt, Wc, bc, out);
}

// Round 7
// 250.281 us; speedup vs baseline: 1.0508x; 1.0422x over previous
//
#include <hip/hip_runtime.h>

// Problem constants (match reference)
#define N_NODES 100000
#define N_EDGES 1200000
#define DIM     64
#define BGRAPHS 1000
#define NCLASS  10
#define BN_EPS  1e-5f

// CSR-build partition constants
#define NBUCK   256            // coarse buckets
#define NPB     391            // nodes per bucket (256*391 = 100096 >= N)
#define MAGIC   10984572u      // ceil(2^32/391): bucket = umulhi(d, MAGIC)
#define CHUNK   8192           // edges per partition block
#define NBLK_P  147            // ceil(E / CHUNK)
#define SCAN_N  (NBUCK * NBLK_P)   // 37632
#define CAP     8192           // refine LDS staging capacity (>= max bucket edges)
#define NB_C    3125           // convert blocks: N*DIM/8/256

typedef __attribute__((ext_vector_type(8))) short   bfx8;   // 8 bf16 MFMA A/B frag
typedef __attribute__((ext_vector_type(4))) float   f32x4;  // MFMA C/D frag
typedef __attribute__((ext_vector_type(8))) unsigned short u16x8;

__device__ __forceinline__ unsigned short f2bf(float f) {
    unsigned u = __builtin_bit_cast(unsigned, f);
    unsigned r = (u + 0x7FFFu + ((u >> 16) & 1u)) >> 16;   // RNE
    return (unsigned short)r;
}
__device__ __forceinline__ float bf2f(unsigned short h) {
    unsigned u = ((unsigned)h) << 16;
    return __builtin_bit_cast(float, u);
}

// ---------------------------------------------------------------------------
// Setup (one launch, three block-ranges):
//  [0, NB_C)            : x fp32->bf16, zero xs
//  [NB_C, NB_C+NBLK_P)  : per-chunk bucket histogram -> histc[bucket*NBLK_P+blk]
//  last block           : pack W1a/W1b/W2 transposed bf16 + fold BN
// ---------------------------------------------------------------------------
__global__ __launch_bounds__(256) void setup_kernel(
    const float* __restrict__ x, unsigned short* __restrict__ xbf, float* __restrict__ xs,
    const int* __restrict__ ei, int* __restrict__ histc,
    const float* __restrict__ W1a, const float* __restrict__ W1b, const float* __restrict__ W2,
    const float* __restrict__ b1a,
    const float* __restrict__ g1, const float* __restrict__ be1,
    const float* __restrict__ m1, const float* __restrict__ v1,
    const float* __restrict__ b2,
    const float* __restrict__ g2, const float* __restrict__ be2,
    const float* __restrict__ m2, const float* __restrict__ v2,
    unsigned short* __restrict__ wpA, unsigned short* __restrict__ wpB,
    unsigned short* __restrict__ wpC,
    float* __restrict__ s1, float* __restrict__ o1,
    float* __restrict__ s2, float* __restrict__ o2) {
    int blk = blockIdx.x, t = threadIdx.x;
    if (blk < NB_C) {
        int i = blk * 256 + t;              // < 800000 exactly
        float4 a = ((const float4*)x)[i * 2];
        float4 b = ((const float4*)x)[i * 2 + 1];
        u16x8 o;
        o[0] = f2bf(a.x); o[1] = f2bf(a.y); o[2] = f2bf(a.z); o[3] = f2bf(a.w);
        o[4] = f2bf(b.x); o[5] = f2bf(b.y); o[6] = f2bf(b.z); o[7] = f2bf(b.w);
        ((u16x8*)xbf)[i] = o;
        if (i < BGRAPHS * DIM) xs[i] = 0.f;
        return;
    }
    blk -= NB_C;
    if (blk < NBLK_P) {
        __shared__ int cnt[NBUCK];
        cnt[t] = 0;
        __syncthreads();
        int e0 = blk * CHUNK;
        int eend = e0 + CHUNK; if (eend > N_EDGES) eend = N_EDGES;
        for (int e = e0 + t; e < eend; e += 256) {
            unsigned d = (unsigned)ei[N_EDGES + e];
            atomicAdd(&cnt[__umulhi(d, MAGIC)], 1);
        }
        __syncthreads();
        histc[t * NBLK_P + blk] = cnt[t];
        return;
    }
    // weights + BN fold (single block)
    for (int i = t; i < 3 * 4096; i += 256) {
        int mat = i >> 12, j = i & 4095;
        int col = j >> 6, k = j & 63;
        const float* W = (mat == 0) ? W1a : ((mat == 1) ? W1b : W2);
        unsigned short* wp = (mat == 0) ? wpA : ((mat == 1) ? wpB : wpC);
        wp[j] = f2bf(W[k * 64 + col]);
    }
    if (t < 64) {
        float s = g1[t] * rsqrtf(v1[t] + BN_EPS);
        s1[t] = s;
        o1[t] = b1a[t] * s + (be1[t] - m1[t] * s);
        float sv = g2[t] * rsqrtf(v2[t] + BN_EPS);
        s2[t] = sv;
        o2[t] = b2[t] * sv + (be2[t] - m2[t] * sv);
    }
}

// ---------------------------------------------------------------------------
// Parallel scan chain over SCAN_N = 37632 (per-(bucket,chunk) counts):
// scan1: per-block (1024) exclusive scan; scan2: scan of 37 block sums;
// scan3: add block offsets -> base table.
// ---------------------------------------------------------------------------
__global__ __launch_bounds__(256) void scan1_kernel(const int* __restrict__ in,
                                                    int* __restrict__ outp,
                                                    int* __restrict__ bsum, int n) {
    __shared__ int tmp[256];
    int t = threadIdx.x;
    int base = blockIdx.x * 1024;
    int v[4]; int s = 0;
    #pragma unroll
    for (int j = 0; j < 4; ++j) {
        int idx = base + t * 4 + j;
        v[j] = (idx < n) ? in[idx] : 0;
        s += v[j];
    }
    tmp[t] = s;
    __syncthreads();
    for (int off = 1; off < 256; off <<= 1) {
        int a = (t >= off) ? tmp[t - off] : 0;
        __syncthreads();
        tmp[t] += a;
        __syncthreads();
    }
    int excl = tmp[t] - s;
    if (t == 255) bsum[blockIdx.x] = tmp[255];
    int run = excl;
    #pragma unroll
    for (int j = 0; j < 4; ++j) {
        int idx = base + t * 4 + j;
        if (idx < n) outp[idx] = run;
        run += v[j];
    }
}

__global__ __launch_bounds__(128) void scan2_kernel(int* __restrict__ bsum, int nb) {
    __shared__ int tmp[128];
    int t = threadIdx.x;
    int v = (t < nb) ? bsum[t] : 0;
    tmp[t] = v;
    __syncthreads();
    for (int off = 1; off < 128; off <<= 1) {
        int a = (t >= off) ? tmp[t - off] : 0;
        __syncthreads();
        tmp[t] += a;
        __syncthreads();
    }
    if (t < nb) bsum[t] = tmp[t] - v;
}

__global__ void scan3_kernel(int* __restrict__ arr, const int* __restrict__ bsum, int n) {
    int i = blockIdx.x * blockDim.x + threadIdx.x;
    if (i < n) arr[i] += bsum[i >> 10];
}

// ---------------------------------------------------------------------------
// part: scatter (src, dst_local) into bucket regions using precomputed
// per-(bucket,chunk) base offsets (single dst pass, LDS cursors only).
// ---------------------------------------------------------------------------
__global__ __launch_bounds__(256) void part_kernel(const int* __restrict__ ei,
                                                   const int* __restrict__ base,
                                                   int* __restrict__ srcbuf,
                                                   unsigned short* __restrict__ dstlbuf) {
    __shared__ int cur[NBUCK];
    int t = threadIdx.x, blk = blockIdx.x;
    cur[t] = base[t * NBLK_P + blk];
    __syncthreads();
    int e0 = blk * CHUNK;
    int eend = e0 + CHUNK; if (eend > N_EDGES) eend = N_EDGES;
    for (int e = e0 + t; e < eend; e += 256) {
        unsigned d = (unsigned)ei[N_EDGES + e];
        int s = ei[e];
        int b = __umulhi(d, MAGIC);
        int pos = atomicAdd(&cur[b], 1);
        srcbuf[pos] = s;
        dstlbuf[pos] = (unsigned short)(d - b * NPB);
    }
}

// ---------------------------------------------------------------------------
// refine: one block per bucket; LDS counting sort by dst_local; coalesced
// csr_src write; emits rowptr from the local exclusive scan.
// ---------------------------------------------------------------------------
__global__ __launch_bounds__(256) void refine_kernel(const int* __restrict__ srcbuf,
                                                     const unsigned short* __restrict__ dstlbuf,
                                                     const int* __restrict__ base,
                                                     int* __restrict__ csr_src,
                                                     int* __restrict__ rowptr) {
    __shared__ int cnt[NPB + 1];
    __shared__ int cur[NPB + 1];
    __shared__ int tmp[256];
    __shared__ int outb[CAP];
    int t = threadIdx.x, b = blockIdx.x;
    int beg = base[b * NBLK_P];
    int end = (b == NBUCK - 1) ? N_EDGES : base[(b + 1) * NBLK_P];

    for (int i = t; i < NPB + 1; i += 256) cnt[i] = 0;
    __syncthreads();
    for (int i = beg + t; i < end; i += 256)
        atomicAdd(&cnt[dstlbuf[i]], 1);
    __syncthreads();

    int i0 = 2 * t, i1 = 2 * t + 1;
    int v0 = (i0 < NPB) ? cnt[i0] : 0;
    int v1 = (i1 < NPB) ? cnt[i1] : 0;
    int s = v0 + v1;
    tmp[t] = s;
    __syncthreads();
    for (int off = 1; off < 256; off <<= 1) {
        int a = (t >= off) ? tmp[t - off] : 0;
        __syncthreads();
        tmp[t] += a;
        __syncthreads();
    }
    int excl = tmp[t] - s;
    if (i0 < NPB) cur[i0] = excl;
    if (i1 < NPB) cur[i1] = excl + v0;
    {
        int g0 = b * NPB + i0;
        if (i0 < NPB && g0 < N_NODES) rowptr[g0] = beg + excl;
        int g1 = b * NPB + i1;
        if (i1 < NPB && g1 < N_NODES) rowptr[g1] = beg + excl + v0;
    }
    if (b == NBUCK - 1 && t == 0) rowptr[N_NODES] = N_EDGES;
    __syncthreads();

    for (int i = beg + t; i < end; i += 256) {
        int dl = dstlbuf[i];
        int pos = atomicAdd(&cur[dl], 1);
        if (pos < CAP) outb[pos] = srcbuf[i];
    }
    __syncthreads();

    int nb = end - beg; if (nb > CAP) nb = CAP;
    for (int i = t; i < nb; i += 256) csr_src[beg + i] = outb[i];
}

// ---------------------------------------------------------------------------
// bf16 gather: out[i] = feat[i] + sum_{s in nbrs(i)} feat[s]
// 8 lanes/node (16B/lane), 32 nodes per block; neighbor loop unrolled x4
// for memory-level parallelism.
// ---------------------------------------------------------------------------
__global__ __launch_bounds__(256) void gather_kernel(const unsigned short* __restrict__ feat,
                                                     const int* __restrict__ rowptr,
                                                     const int* __restrict__ csr_src,
                                                     unsigned short* __restrict__ out) {
    int t = threadIdx.x;
    int node = blockIdx.x * 32 + (t >> 3);
    int q = t & 7;
    if (node >= N_NODES) return;
    const u16x8* f8 = (const u16x8*)feat;
    u16x8 sv = f8[(long long)node * 8 + q];
    float acc[8];
    #pragma unroll
    for (int j = 0; j < 8; ++j) acc[j] = bf2f(sv[j]);
    int k = rowptr[node], end = rowptr[node + 1];
    for (; k + 4 <= end; k += 4) {
        int s0 = csr_src[k], s1 = csr_src[k + 1], s2 = csr_src[k + 2], s3 = csr_src[k + 3];
        u16x8 v0 = f8[(long long)s0 * 8 + q];
        u16x8 v1 = f8[(long long)s1 * 8 + q];
        u16x8 v2 = f8[(long long)s2 * 8 + q];
        u16x8 v3 = f8[(long long)s3 * 8 + q];
        #pragma unroll
        for (int j = 0; j < 8; ++j)
            acc[j] += (bf2f(v0[j]) + bf2f(v1[j])) + (bf2f(v2[j]) + bf2f(v3[j]));
    }
    for (; k < end; ++k) {
        int sc = csr_src[k];
        u16x8 v = f8[(long long)sc * 8 + q];
        #pragma unroll
        for (int j = 0; j < 8; ++j) acc[j] += bf2f(v[j]);
    }
    u16x8 o;
    #pragma unroll
    for (int j = 0; j < 8; ++j) o[j] = f2bf(acc[j]);
    ((u16x8*)out)[(long long)node * 8 + q] = o;
}

// ---------------------------------------------------------------------------
// MFMA conv1 MLP (packed bf16 weights, folded BN):
//   h2 = relu(relu(bn1(h0 @ W1a)) @ W1b + b1b)
// ---------------------------------------------------------------------------
__global__ __launch_bounds__(256) void mlp1_kernel(
    const unsigned short* __restrict__ h0,
    const unsigned short* __restrict__ wpA, const unsigned short* __restrict__ wpB,
    const float* __restrict__ s1, const float* __restrict__ o1,
    const float* __restrict__ b1b,
    unsigned short* __restrict__ h2) {
    __shared__ unsigned short h1t[4][16 * 72];   // stride 72 (144B, 16B-aligned)
    __shared__ unsigned short outt[4][16 * 64];

    int t = threadIdx.x;
    int w = t >> 6, lane = t & 63;
    int m = lane & 15, q = lane >> 4;
    int row0 = blockIdx.x * 64 + w * 16;

    int r = row0 + m;
    if (r > N_NODES - 1) r = N_NODES - 1;
    const bfx8* ap = (const bfx8*)(h0 + (long long)r * 64);
    bfx8 a0 = ap[q];
    bfx8 a1 = ap[4 + q];

    const bfx8* wA8 = (const bfx8*)wpA;
    const bfx8* wB8 = (const bfx8*)wpB;

    float A1[4], B1[4], B2c[4];
    #pragma unroll
    for (int nt = 0; nt < 4; ++nt) {
        int c = nt * 16 + m;
        A1[nt] = s1[c];
        B1[nt] = o1[c];
        B2c[nt] = b1b[c];
    }

    f32x4 acc[4];
    #pragma unroll
    for (int nt = 0; nt < 4; ++nt) {
        int cb = (nt * 16 + m) * 8;
        acc[nt] = (f32x4){0.f, 0.f, 0.f, 0.f};
        acc[nt] = __builtin_amdgcn_mfma_f32_16x16x32_bf16(a0, wA8[cb + q], acc[nt], 0, 0, 0);
        acc[nt] = __builtin_amdgcn_mfma_f32_16x16x32_bf16(a1, wA8[cb + 4 + q], acc[nt], 0, 0, 0);
    }
    #pragma unroll
    for (int nt = 0; nt < 4; ++nt)
        #pragma unroll
        for (int rr = 0; rr < 4; ++rr) {
            float v = fmaxf(acc[nt][rr] * A1[nt] + B1[nt], 0.f);
            h1t[w][(q * 4 + rr) * 72 + nt * 16 + m] = f2bf(v);
        }
    __syncthreads();

    const bfx8* hp = (const bfx8*)&h1t[w][m * 72];
    bfx8 c0 = hp[q];
    bfx8 c1 = hp[4 + q];
    f32x4 acc2[4];
    #pragma unroll
    for (int nt = 0; nt < 4; ++nt) {
        int cb = (nt * 16 + m) * 8;
        acc2[nt] = (f32x4){0.f, 0.f, 0.f, 0.f};
        acc2[nt] = __builtin_amdgcn_mfma_f32_16x16x32_bf16(c0, wB8[cb + q], acc2[nt], 0, 0, 0);
        acc2[nt] = __builtin_amdgcn_mfma_f32_16x16x32_bf16(c1, wB8[cb + 4 + q], acc2[nt], 0, 0, 0);
    }
    #pragma unroll
    for (int nt = 0; nt < 4; ++nt)
        #pragma unroll
        for (int rr = 0; rr < 4; ++rr) {
            float v = fmaxf(acc2[nt][rr] + B2c[nt], 0.f);
            outt[w][(q * 4 + rr) * 64 + nt * 16 + m] = f2bf(v);
        }
    __syncthreads();

    #pragma unroll
    for (int i = lane; i < 128; i += 64) {
        int rr = i >> 3, cc = i & 7;
        int rg = row0 + rr;
        if (rg < N_NODES)
            ((float4*)h2)[(long long)rg * 8 + cc] = *(const float4*)&outt[w][rr * 64 + cc * 8];
    }
}

// ---------------------------------------------------------------------------
// MFMA conv2 + pool: h4 = relu(bn2(h3 @ W2)); xs[batch[row]] += h4
// ---------------------------------------------------------------------------
__global__ __launch_bounds__(256) void mlp2_kernel(
    const unsigned short* __restrict__ h3,
    const unsigned short* __restrict__ wpC,
    const float* __restrict__ s2, const float* __restrict__ o2,
    const int* __restrict__ batch,
    float* __restrict__ xs) {
    __shared__ float pool[64 * 64];
    __shared__ int bts[64];

    int t = threadIdx.x;
    int w = t >> 6, lane = t & 63;
    int m = lane & 15, q = lane >> 4;
    int row0b = blockIdx.x * 64;
    int row0 = row0b + w * 16;

    if (t < 64) {
        int rg = row0b + t;
        bts[t] = (rg < N_NODES) ? batch[rg] : -1;
    }

    int r = row0 + m;
    if (r > N_NODES - 1) r = N_NODES - 1;
    const bfx8* ap = (const bfx8*)(h3 + (long long)r * 64);
    bfx8 a0 = ap[q];
    bfx8 a1 = ap[4 + q];

    const bfx8* wC8 = (const bfx8*)wpC;
    float A[4], Bc[4];
    #pragma unroll
    for (int nt = 0; nt < 4; ++nt) {
        int c = nt * 16 + m;
        A[nt] = s2[c];
        Bc[nt] = o2[c];
    }

    f32x4 acc[4];
    #pragma unroll
    for (int nt = 0; nt < 4; ++nt) {
        int cb = (nt * 16 + m) * 8;
        acc[nt] = (f32x4){0.f, 0.f, 0.f, 0.f};
        acc[nt] = __builtin_amdgcn_mfma_f32_16x16x32_bf16(a0, wC8[cb + q], acc[nt], 0, 0, 0);
        acc[nt] = __builtin_amdgcn_mfma_f32_16x16x32_bf16(a1, wC8[cb + 4 + q], acc[nt], 0, 0, 0);
    }
    #pragma unroll
    for (int nt = 0; nt < 4; ++nt)
        #pragma unroll
        for (int rr = 0; rr < 4; ++rr) {
            float v = fmaxf(acc[nt][rr] * A[nt] + Bc[nt], 0.f);
            pool[(w * 16 + q * 4 + rr) * 64 + nt * 16 + m] = v;
        }
    __syncthreads();

    int col = t & 63;
    int r0 = (t >> 6) * 16;
    int cb = bts[r0];
    float cur = 0.f;
    #pragma unroll
    for (int rr = 0; rr < 16; ++rr) {
        int b = bts[r0 + rr];
        if (b != cb) {
            if (cb >= 0) unsafeAtomicAdd(&xs[cb * 64 + col], cur);
            cb = b;
            cur = 0.f;
        }
        cur += pool[(r0 + rr) * 64 + col];
    }
    if (cb >= 0) unsafeAtomicAdd(&xs[cb * 64 + col], cur);
}

// ---------------------------------------------------------------------------
// Head: x_topo = relu(topo @ Wt + bt); out = [x_struct, x_topo] @ Wc + bc
// ---------------------------------------------------------------------------
__global__ __launch_bounds__(64) void head_kernel(
    const float* __restrict__ xs, const float* __restrict__ topo,
    const float* __restrict__ Wt, const float* __restrict__ bt,
    const float* __restrict__ Wc, const float* __restrict__ bc,
    float* __restrict__ out) {
    __shared__ float trow[64];
    __shared__ float comb[128];
    int b = blockIdx.x;
    int h = threadIdx.x;
    trow[h] = topo[b * 64 + h];
    __syncthreads();
    float acc = bt[h];
    #pragma unroll
    for (int k = 0; k < 64; ++k) acc += trow[k] * Wt[k * 64 + h];
    comb[h] = xs[b * 64 + h];
    comb[64 + h] = fmaxf(acc, 0.f);
    __syncthreads();
    if (h < NCLASS) {
        float o = bc[h];
        #pragma unroll
        for (int k = 0; k < 128; ++k) o += comb[k] * Wc[k * NCLASS + h];
        out[b * NCLASS + h] = o;
    }
}

// ---------------------------------------------------------------------------
extern "C" void kernel_launch(void* const* d_in, const int* in_sizes, int n_in,
                              void* d_out, int out_size, void* d_ws, size_t ws_size,
                              hipStream_t stream) {
    const float* x     = (const float*)d_in[0];
    const int*   ei    = (const int*)d_in[1];
    const int*   batch = (const int*)d_in[2];
    const float* topo  = (const float*)d_in[3];
    const float* W1a   = (const float*)d_in[4];
    const float* b1a   = (const float*)d_in[5];
    const float* g1    = (const float*)d_in[6];
    const float* be1   = (const float*)d_in[7];
    const float* m1    = (const float*)d_in[8];
    const float* v1    = (const float*)d_in[9];
    const float* W1b   = (const float*)d_in[10];
    const float* b1b   = (const float*)d_in[11];
    const float* W2    = (const float*)d_in[12];
    const float* b2    = (const float*)d_in[13];
    const float* g2    = (const float*)d_in[14];
    const float* be2   = (const float*)d_in[15];
    const float* m2    = (const float*)d_in[16];
    const float* v2    = (const float*)d_in[17];
    const float* Wt    = (const float*)d_in[18];
    const float* bt    = (const float*)d_in[19];
    const float* Wc    = (const float*)d_in[20];
    const float* bc    = (const float*)d_in[21];
    float* out = (float*)d_out;

    // Workspace layout (16B-aligned chunks)
    char* p = (char*)d_ws;
    unsigned short* xbf  = (unsigned short*)p; p += (size_t)N_NODES * DIM * 2;  // 12.8 MB
    unsigned short* bufA = (unsigned short*)p; p += (size_t)N_NODES * DIM * 2;  // 12.8 MB
    unsigned short* bufB = (unsigned short*)p; p += (size_t)N_NODES * DIM * 2;  // 12.8 MB
    float* xs      = (float*)p; p += (size_t)BGRAPHS * DIM * 4;                 // 256 KB
    int*   rowptr  = (int*)p;   p += (size_t)(N_NODES + 16) * 4;                // 400 KB
    int*   histc   = (int*)p;   p += (size_t)(SCAN_N + 16) * 4;                 // 150 KB
    int*   base    = (int*)p;   p += (size_t)(SCAN_N + 16) * 4;                 // 150 KB
    int*   bsum    = (int*)p;   p += 256 * 4;
    int*   srcbuf  = (int*)p;   p += (size_t)N_EDGES * 4;                       // 4.8 MB
    unsigned short* dstlbuf = (unsigned short*)p; p += (size_t)N_EDGES * 2;     // 2.4 MB
    int*   csr_src = (int*)p;   p += (size_t)N_EDGES * 4;                       // 4.8 MB
    unsigned short* wpA = (unsigned short*)p; p += 4096 * 2;
    unsigned short* wpB = (unsigned short*)p; p += 4096 * 2;
    unsigned short* wpC = (unsigned short*)p; p += 4096 * 2;
    float* s1 = (float*)p; p += 64 * 4;
    float* o1 = (float*)p; p += 64 * 4;
    float* s2 = (float*)p; p += 64 * 4;
    float* o2 = (float*)p; p += 64 * 4;

    const int NB_S1 = (SCAN_N + 1023) / 1024;   // 37
    const int NB_S3 = (SCAN_N + 255) / 256;     // 147

    setup_kernel<<<NB_C + NBLK_P + 1, 256, 0, stream>>>(
        x, xbf, xs, ei, histc,
        W1a, W1b, W2, b1a, g1, be1, m1, v1, b2, g2, be2, m2, v2,
        wpA, wpB, wpC, s1, o1, s2, o2);
    scan1_kernel<<<NB_S1, 256, 0, stream>>>(histc, base, bsum, SCAN_N);
    scan2_kernel<<<1, 128, 0, stream>>>(bsum, NB_S1);
    scan3_kernel<<<NB_S3, 256, 0, stream>>>(base, bsum, SCAN_N);
    part_kernel<<<NBLK_P, 256, 0, stream>>>(ei, base, srcbuf, dstlbuf);
    refine_kernel<<<NBUCK, 256, 0, stream>>>(srcbuf, dstlbuf, base, csr_src, rowptr);

    // agg1: bufA = xbf + scatter(xbf)
    gather_kernel<<<(N_NODES + 31) / 32, 256, 0, stream>>>(xbf, rowptr, csr_src, bufA);
    // conv1 MLP (MFMA, packed weights): bufB = h2
    mlp1_kernel<<<(N_NODES + 63) / 64, 256, 0, stream>>>(
        bufA, wpA, wpB, s1, o1, b1b, bufB);
    // agg2: bufA = h2 + scatter(h2)
    gather_kernel<<<(N_NODES + 31) / 32, 256, 0, stream>>>(bufB, rowptr, csr_src, bufA);
    // conv2 + pool (MFMA)
    mlp2_kernel<<<(N_NODES + 63) / 64, 256, 0, stream>>>(
        bufA, wpC, s2, o2, batch, xs);
    // head
    head_kernel<<<BGRAPHS, 64, 0, stream>>>(xs, topo, Wt, bt, Wc, bc, out);
}